// Round 2
// baseline (183.177 us; speedup 1.0000x reference)
//
#include <hip/hip_runtime.h>

#define POOLK 7
#define NBINS 49            // POOLK*POOLK
#define ALPHA 32
#define C4N   8             // ALPHA/4
#define HH    128
#define WW    128
#define NUM_ROIS 4096
#define F4_PER_PIX (NBINS * C4N)   // 392 float4 per (y,x) pixel

// img:  (1, 128, 128, 1568) f32  -> feat (128,128,49,32)
// rois: (1, 4096, 4) f32         -> (xmin, ymin, xmax, ymax) == one float4
// out:  (1, 4096, 7, 7, 32) f32  -> flat: rg*32 + c, rg = roi*49 + g, g = p*7+q
__global__ __launch_bounds__(256) void psroi_align_kernel(
    const float* __restrict__ img,
    const float4* __restrict__ rois4,
    float4* __restrict__ out4)
{
    const int tid = blockIdx.x * blockDim.x + threadIdx.x;
    const int c4  = tid & (C4N - 1);       // which float4 of the 32 channels
    const int rg  = tid >> 3;              // roi*49 + g
    const int g   = rg % NBINS;
    const int roi = rg / NBINS;

    const float4 r = rois4[roi];           // x=xmin y=ymin z=xmax w=ymax

    const float step_x = (r.z - r.x) * (1.0f / POOLK);
    const float step_y = (r.w - r.y) * (1.0f / POOLK);

    const int p = g / POOLK;               // x bin
    const int q = g % POOLK;               // y bin

    const float x1 = r.x + (float)p * step_x;
    const float y1 = r.y + (float)q * step_y;

    const float scale = (float)(HH - 1);   // 127
    // 2 sample coords per axis (t = 0, 1 -> bin corners)
    float ys[2], xs[2];
    ys[0] = y1 * scale;
    ys[1] = (y1 + step_y) * scale;
    xs[0] = x1 * scale;
    xs[1] = (x1 + step_x) * scale;

    // Per-axis: floor, weight, clamped indices, validity
    float wy[2], wx[2];
    bool  vy[2], vx[2];
    int   yrow[4], xcol[4];                // {y0(s0),y1(s0),y0(s1),y1(s1)}
    #pragma unroll
    for (int s = 0; s < 2; ++s) {
        const float yg = ys[s];
        vy[s] = (yg >= 0.0f) && (yg <= (float)(HH - 1));
        const float y0f = floorf(yg);
        wy[s] = yg - y0f;
        int y0 = min(max((int)y0f, 0), HH - 1);
        yrow[2 * s]     = y0;
        yrow[2 * s + 1] = min(y0 + 1, HH - 1);

        const float xg = xs[s];
        vx[s] = (xg >= 0.0f) && (xg <= (float)(WW - 1));
        const float x0f = floorf(xg);
        wx[s] = xg - x0f;
        int x0 = min(max((int)x0f, 0), WW - 1);
        xcol[2 * s]     = x0;
        xcol[2 * s + 1] = min(x0 + 1, WW - 1);
    }

    const float4* __restrict__ feat = (const float4*)img;
    const int gbase = g * C4N + c4;

    int rowoff[4], coloff[4];
    #pragma unroll
    for (int i = 0; i < 4; ++i) {
        rowoff[i] = yrow[i] * (WW * F4_PER_PIX) + gbase;
        coloff[i] = xcol[i] * F4_PER_PIX;
    }

    // Issue ALL 16 texel loads before consuming any: 4 rows x 4 cols
    float4 ld[16];
    #pragma unroll
    for (int rr = 0; rr < 4; ++rr) {
        #pragma unroll
        for (int cc = 0; cc < 4; ++cc) {
            ld[rr * 4 + cc] = feat[rowoff[rr] + coloff[cc]];
        }
    }

    float4 vmax;
    vmax.x = -INFINITY; vmax.y = -INFINITY; vmax.z = -INFINITY; vmax.w = -INFINITY;

    #pragma unroll
    for (int sy = 0; sy < 2; ++sy) {
        #pragma unroll
        for (int sx = 0; sx < 2; ++sx) {
            const float w11 = wy[sy] * wx[sx];
            const float w10 = wy[sy] - w11;            // wy*(1-wx)
            const float w01 = wx[sx] - w11;            // (1-wy)*wx
            const float w00 = 1.0f - wy[sy] - wx[sx] + w11;

            const float4 v00 = ld[(2 * sy)     * 4 + (2 * sx)];
            const float4 v01 = ld[(2 * sy)     * 4 + (2 * sx + 1)];
            const float4 v10 = ld[(2 * sy + 1) * 4 + (2 * sx)];
            const float4 v11 = ld[(2 * sy + 1) * 4 + (2 * sx + 1)];

            float4 v;
            v.x = v00.x * w00 + v01.x * w01 + v10.x * w10 + v11.x * w11;
            v.y = v00.y * w00 + v01.y * w01 + v10.y * w10 + v11.y * w11;
            v.z = v00.z * w00 + v01.z * w01 + v10.z * w10 + v11.z * w11;
            v.w = v00.w * w00 + v01.w * w01 + v10.w * w10 + v11.w * w11;

            if (!(vy[sy] && vx[sx])) { v.x = 0.0f; v.y = 0.0f; v.z = 0.0f; v.w = 0.0f; }

            vmax.x = fmaxf(vmax.x, v.x);
            vmax.y = fmaxf(vmax.y, v.y);
            vmax.z = fmaxf(vmax.z, v.z);
            vmax.w = fmaxf(vmax.w, v.w);
        }
    }

    out4[tid] = vmax;
}

extern "C" void kernel_launch(void* const* d_in, const int* in_sizes, int n_in,
                              void* d_out, int out_size, void* d_ws, size_t ws_size,
                              hipStream_t stream) {
    const float* img   = (const float*)d_in[0];
    const float4* rois = (const float4*)d_in[1];
    float4* out = (float4*)d_out;

    const int total_threads = NUM_ROIS * NBINS * C4N;   // 1,605,632 (divisible by 256)
    const int block = 256;
    const int grid  = total_threads / block;            // 6272
    psroi_align_kernel<<<grid, block, 0, stream>>>(img, rois, out);
}

// Round 3
// 182.937 us; speedup vs baseline: 1.0013x; 1.0013x over previous
//
#include <hip/hip_runtime.h>

#define POOLK 7
#define NBINS 49            // POOLK*POOLK
#define ALPHA 32
#define C4N   8             // ALPHA/4
#define HH    128
#define WW    128
#define NUM_ROIS 4096
#define F4_PER_PIX (NBINS * C4N)   // 392 float4 per (y,x) pixel

// img:  (1, 128, 128, 1568) f32  -> feat (128,128,49,32)
// rois: (1, 4096, 4) f32         -> (xmin, ymin, xmax, ymax) == one float4
// out:  (1, 4096, 7, 7, 32) f32  -> flat: rg*32 + c, rg = roi*49 + g, g = p*7+q
__global__ __launch_bounds__(256) void psroi_align_kernel(
    const float4* __restrict__ feat,
    const float4* __restrict__ rois4,
    float4* __restrict__ out4)
{
    const int tid = blockIdx.x * blockDim.x + threadIdx.x;
    const int c4  = tid & (C4N - 1);       // which float4 of the 32 channels
    const int rg  = tid >> 3;              // roi*49 + g
    const int g   = rg % NBINS;
    const int roi = rg / NBINS;

    const float4 r = rois4[roi];           // x=xmin y=ymin z=xmax w=ymax

    const float step_x = (r.z - r.x) * (1.0f / POOLK);
    const float step_y = (r.w - r.y) * (1.0f / POOLK);

    const int p = g / POOLK;               // x bin
    const int q = g % POOLK;               // y bin

    const float x1 = r.x + (float)p * step_x;
    const float y1 = r.y + (float)q * step_y;

    const float scale = (float)(HH - 1);   // 127
    float ys[2], xs[2];
    ys[0] = y1 * scale;
    ys[1] = (y1 + step_y) * scale;
    xs[0] = x1 * scale;
    xs[1] = (x1 + step_x) * scale;

    float wy[2], wx[2];
    bool  vy[2], vx[2];
    int   yrow[4], xcol[4];                // {lo(s0),hi(s0),lo(s1),hi(s1)}
    #pragma unroll
    for (int s = 0; s < 2; ++s) {
        const float yg = ys[s];
        vy[s] = (yg >= 0.0f) && (yg <= (float)(HH - 1));
        const float y0f = floorf(yg);
        wy[s] = yg - y0f;
        int y0 = min(max((int)y0f, 0), HH - 1);
        yrow[2 * s]     = y0;
        yrow[2 * s + 1] = min(y0 + 1, HH - 1);

        const float xg = xs[s];
        vx[s] = (xg >= 0.0f) && (xg <= (float)(WW - 1));
        const float x0f = floorf(xg);
        wx[s] = xg - x0f;
        int x0 = min(max((int)x0f, 0), WW - 1);
        xcol[2 * s]     = x0;
        xcol[2 * s + 1] = min(x0 + 1, WW - 1);
    }

    const int gbase = g * C4N + c4;

    // Flat float4 indices for all 16 texels, grouped by sample (consumption order):
    // sample s = sy*2+sx uses rows {2sy, 2sy+1} x cols {2sx, 2sx+1}
    int idx[16];
    #pragma unroll
    for (int sy = 0; sy < 2; ++sy) {
        #pragma unroll
        for (int sx = 0; sx < 2; ++sx) {
            const int s = sy * 2 + sx;
            const int r0 = yrow[2 * sy]     * (WW * F4_PER_PIX) + gbase;
            const int r1 = yrow[2 * sy + 1] * (WW * F4_PER_PIX) + gbase;
            const int c0 = xcol[2 * sx]     * F4_PER_PIX;
            const int c1 = xcol[2 * sx + 1] * F4_PER_PIX;
            idx[s * 4 + 0] = r0 + c0;
            idx[s * 4 + 1] = r0 + c1;
            idx[s * 4 + 2] = r1 + c0;
            idx[s * 4 + 3] = r1 + c1;
        }
    }

    // Issue ALL 16 loads, in consumption order, before any consumption.
    float4 ld[16];
    #pragma unroll
    for (int i = 0; i < 16; ++i) {
        ld[i] = feat[idx[i]];
    }
    // Hard fence: nothing (especially the weighted-sum consumption) may be
    // scheduled between/above the loads. Forces 16 loads in flight per thread.
    __builtin_amdgcn_sched_barrier(0);

    float4 vmax;
    vmax.x = -INFINITY; vmax.y = -INFINITY; vmax.z = -INFINITY; vmax.w = -INFINITY;

    #pragma unroll
    for (int sy = 0; sy < 2; ++sy) {
        #pragma unroll
        for (int sx = 0; sx < 2; ++sx) {
            const int s = sy * 2 + sx;
            const float w11 = wy[sy] * wx[sx];
            const float w10 = wy[sy] - w11;            // wy*(1-wx)
            const float w01 = wx[sx] - w11;            // (1-wy)*wx
            const float w00 = 1.0f - wy[sy] - wx[sx] + w11;

            const float4 v00 = ld[s * 4 + 0];
            const float4 v01 = ld[s * 4 + 1];
            const float4 v10 = ld[s * 4 + 2];
            const float4 v11 = ld[s * 4 + 3];

            float4 v;
            v.x = v00.x * w00 + v01.x * w01 + v10.x * w10 + v11.x * w11;
            v.y = v00.y * w00 + v01.y * w01 + v10.y * w10 + v11.y * w11;
            v.z = v00.z * w00 + v01.z * w01 + v10.z * w10 + v11.z * w11;
            v.w = v00.w * w00 + v01.w * w01 + v10.w * w10 + v11.w * w11;

            if (!(vy[sy] && vx[sx])) { v.x = 0.0f; v.y = 0.0f; v.z = 0.0f; v.w = 0.0f; }

            vmax.x = fmaxf(vmax.x, v.x);
            vmax.y = fmaxf(vmax.y, v.y);
            vmax.z = fmaxf(vmax.z, v.z);
            vmax.w = fmaxf(vmax.w, v.w);
        }
    }

    out4[tid] = vmax;
}

extern "C" void kernel_launch(void* const* d_in, const int* in_sizes, int n_in,
                              void* d_out, int out_size, void* d_ws, size_t ws_size,
                              hipStream_t stream) {
    const float4* feat = (const float4*)d_in[0];
    const float4* rois = (const float4*)d_in[1];
    float4* out = (float4*)d_out;

    const int total_threads = NUM_ROIS * NBINS * C4N;   // 1,605,632 (divisible by 256)
    const int block = 256;
    const int grid  = total_threads / block;            // 6272
    psroi_align_kernel<<<grid, block, 0, stream>>>(feat, rois, out);
}

// Round 4
// 164.990 us; speedup vs baseline: 1.1102x; 1.1088x over previous
//
#include <hip/hip_runtime.h>

#define POOLK 7
#define NBINS 49            // POOLK*POOLK
#define ALPHA 32
#define C4N   8             // ALPHA/4
#define HH    128
#define WW    128
#define NUM_ROIS 4096
#define F4_PER_PIX (NBINS * C4N)   // 392 float4 per (y,x) pixel
#define NXCD 8
#define SLOTS_PER_XCD 784          // 6272 / 8
#define CHUNKS_PER_PLANE 128       // 4096 rois * 8 c4 / 256 threads

// img:  (1, 128, 128, 1568) f32  -> feat (128,128,49,32)
// rois: (1, 4096, 4) f32         -> (xmin, ymin, xmax, ymax) == one float4
// out:  (1, 4096, 7, 7, 32) f32  -> flat: rg*32 + c, rg = roi*49 + g, g = p*7+q
//
// Block mapping for L2 locality: XCDs get blocks round-robin (bid % 8).
// Give each XCD a CONTIGUOUS band of (plane, roi-chunk) slots so the
// concurrently-resident blocks on one XCD read ~1 bin-plane (2.1 MB),
// which fits the XCD's 4-MB L2.
__global__ __launch_bounds__(256) void psroi_align_kernel(
    const float4* __restrict__ feat,
    const float4* __restrict__ rois4,
    float4* __restrict__ out4)
{
    const int bid   = blockIdx.x;
    const int xcd   = bid & (NXCD - 1);
    const int j     = bid >> 3;                 // per-XCD sequence 0..783
    const int s     = xcd * SLOTS_PER_XCD + j;  // global slot, contiguous per XCD
    const int g     = s >> 7;                   // plane 0..48 (s / 128)
    const int chunk = s & (CHUNKS_PER_PLANE - 1);
    const int t     = (chunk << 8) + threadIdx.x;   // 0..32767 within plane
    const int c4    = t & (C4N - 1);
    const int roi   = t >> 3;

    const float4 r = rois4[roi];           // x=xmin y=ymin z=xmax w=ymax

    const float step_x = (r.z - r.x) * (1.0f / POOLK);
    const float step_y = (r.w - r.y) * (1.0f / POOLK);

    const int p = g / POOLK;               // x bin
    const int q = g % POOLK;               // y bin

    const float x1 = r.x + (float)p * step_x;
    const float y1 = r.y + (float)q * step_y;

    const float scale = (float)(HH - 1);   // 127
    float ys[2], xs[2];
    ys[0] = y1 * scale;
    ys[1] = (y1 + step_y) * scale;
    xs[0] = x1 * scale;
    xs[1] = (x1 + step_x) * scale;

    float wy[2], wx[2];
    bool  vy[2], vx[2];
    int   yrow[4], xcol[4];                // {lo(s0),hi(s0),lo(s1),hi(s1)}
    #pragma unroll
    for (int sa = 0; sa < 2; ++sa) {
        const float yg = ys[sa];
        vy[sa] = (yg >= 0.0f) && (yg <= (float)(HH - 1));
        const float y0f = floorf(yg);
        wy[sa] = yg - y0f;
        int y0 = min(max((int)y0f, 0), HH - 1);
        yrow[2 * sa]     = y0;
        yrow[2 * sa + 1] = min(y0 + 1, HH - 1);

        const float xg = xs[sa];
        vx[sa] = (xg >= 0.0f) && (xg <= (float)(WW - 1));
        const float x0f = floorf(xg);
        wx[sa] = xg - x0f;
        int x0 = min(max((int)x0f, 0), WW - 1);
        xcol[2 * sa]     = x0;
        xcol[2 * sa + 1] = min(x0 + 1, WW - 1);
    }

    const int gbase = g * C4N + c4;

    int rowoff[4], coloff[4];
    #pragma unroll
    for (int i = 0; i < 4; ++i) {
        rowoff[i] = yrow[i] * (WW * F4_PER_PIX) + gbase;
        coloff[i] = xcol[i] * F4_PER_PIX;
    }

    float4 ld[16];
    #pragma unroll
    for (int rr = 0; rr < 4; ++rr) {
        #pragma unroll
        for (int cc = 0; cc < 4; ++cc) {
            ld[rr * 4 + cc] = feat[rowoff[rr] + coloff[cc]];
        }
    }

    float4 vmax;
    vmax.x = -INFINITY; vmax.y = -INFINITY; vmax.z = -INFINITY; vmax.w = -INFINITY;

    #pragma unroll
    for (int sy = 0; sy < 2; ++sy) {
        #pragma unroll
        for (int sx = 0; sx < 2; ++sx) {
            const float w11 = wy[sy] * wx[sx];
            const float w10 = wy[sy] - w11;            // wy*(1-wx)
            const float w01 = wx[sx] - w11;            // (1-wy)*wx
            const float w00 = 1.0f - wy[sy] - wx[sx] + w11;

            const float4 v00 = ld[(2 * sy)     * 4 + (2 * sx)];
            const float4 v01 = ld[(2 * sy)     * 4 + (2 * sx + 1)];
            const float4 v10 = ld[(2 * sy + 1) * 4 + (2 * sx)];
            const float4 v11 = ld[(2 * sy + 1) * 4 + (2 * sx + 1)];

            float4 v;
            v.x = v00.x * w00 + v01.x * w01 + v10.x * w10 + v11.x * w11;
            v.y = v00.y * w00 + v01.y * w01 + v10.y * w10 + v11.y * w11;
            v.z = v00.z * w00 + v01.z * w01 + v10.z * w10 + v11.z * w11;
            v.w = v00.w * w00 + v01.w * w01 + v10.w * w10 + v11.w * w11;

            if (!(vy[sy] && vx[sx])) { v.x = 0.0f; v.y = 0.0f; v.z = 0.0f; v.w = 0.0f; }

            vmax.x = fmaxf(vmax.x, v.x);
            vmax.y = fmaxf(vmax.y, v.y);
            vmax.z = fmaxf(vmax.z, v.z);
            vmax.w = fmaxf(vmax.w, v.w);
        }
    }

    // out float4 index: (roi*49 + g)*8 + c4 ; lanes 0..7 (same roi) write 128 B contig
    out4[(roi * NBINS + g) * C4N + c4] = vmax;
}

extern "C" void kernel_launch(void* const* d_in, const int* in_sizes, int n_in,
                              void* d_out, int out_size, void* d_ws, size_t ws_size,
                              hipStream_t stream) {
    const float4* feat = (const float4*)d_in[0];
    const float4* rois = (const float4*)d_in[1];
    float4* out = (float4*)d_out;

    const int grid = NXCD * SLOTS_PER_XCD;   // 6272 blocks, 256 thr each
    psroi_align_kernel<<<grid, 256, 0, stream>>>(feat, rois, out);
}